// Round 4
// baseline (233.643 us; speedup 1.0000x reference)
//
#include <hip/hip_runtime.h>
#include <math.h>

#define NB 8
#define NCH 30
#define LL 16384
#define N1 6000
#define N2 4914
#define NCLS 5
#define KLIM 8192
#define ATT_K 13

typedef float f32x4 __attribute__((ext_vector_type(4)));

__device__ __forceinline__ unsigned fkey(float f) {
  unsigned u = __float_as_uint(f);
  unsigned m = (unsigned)(((int)u) >> 31) | 0x80000000u;
  return u ^ m;  // order-preserving float->uint
}
__device__ __forceinline__ float sigmoidf(float x) { return 1.f / (1.f + expf(-x)); }

// ---- K1: per-(b,c) mean pool over HxH = 16384 ----
__global__ void k_pool(const float* __restrict__ adj, float* __restrict__ pooled) {
  int bc = blockIdx.x;                       // 0..239
  const float* p = adj + (size_t)bc * LL;
  int tid = threadIdx.x;
  float s = 0.f;
  #pragma unroll
  for (int it = 0; it < LL / (256 * 4); ++it) {
    float4 v = *(const float4*)(p + it * 1024 + tid * 4);
    s += v.x + v.y + v.z + v.w;
  }
  #pragma unroll
  for (int m = 1; m < 64; m <<= 1) s += __shfl_xor(s, m);
  __shared__ float red[4];
  if ((tid & 63) == 0) red[tid >> 6] = s;
  __syncthreads();
  if (tid == 0) pooled[bc] = (red[0] + red[1] + red[2] + red[3]) * (1.f / (float)LL);
}

// ---- K2 (fused eca+wsum): per-block recompute ECA scale from pooled, then
//      y[b,j] = sum_c adj[b,c,j]*scale[b,c]; per-block partial min/max ----
__global__ void k_wsum(const float* __restrict__ adj, const float* __restrict__ pooled,
                       const float* __restrict__ ew, float* __restrict__ y,
                       float* __restrict__ pmm, float* __restrict__ band_out) {
  int blk = blockIdx.x;                       // b*16 + tile
  int b = blk >> 4, tile = blk & 15;
  int tid = threadIdx.x;
  __shared__ float sc[NCH];
  if (tid < NCH) {
    int c = tid;
    const float* p = pooled + b * NCH;
    float s = ew[1] * p[c];
    if (c > 0)       s += ew[0] * p[c - 1];
    if (c < NCH - 1) s += ew[2] * p[c + 1];
    float scv = sigmoidf(s);
    sc[c] = scv;
    if (tile == 0) band_out[b * NCH + c] = scv;
  }
  __syncthreads();
  int j = tile * 1024 + tid * 4;
  const float* base = adj + (size_t)b * NCH * LL + j;
  float4 acc = {0.f, 0.f, 0.f, 0.f};
  #pragma unroll
  for (int c = 0; c < NCH; ++c) {
    float4 v = *(const float4*)(base + (size_t)c * LL);
    float s = sc[c];
    acc.x += v.x * s; acc.y += v.y * s; acc.z += v.z * s; acc.w += v.w * s;
  }
  *(float4*)(y + b * LL + j) = acc;
  float mn = fminf(fminf(acc.x, acc.y), fminf(acc.z, acc.w));
  float mx = fmaxf(fmaxf(acc.x, acc.y), fmaxf(acc.z, acc.w));
  #pragma unroll
  for (int m = 1; m < 64; m <<= 1) {
    mn = fminf(mn, __shfl_xor(mn, m));
    mx = fmaxf(mx, __shfl_xor(mx, m));
  }
  __shared__ float wmn[4], wmx[4];
  if ((tid & 63) == 0) { wmn[tid >> 6] = mn; wmx[tid >> 6] = mx; }
  __syncthreads();
  if (tid == 0) {
    mn = fminf(fminf(wmn[0], wmn[1]), fminf(wmn[2], wmn[3]));
    mx = fmaxf(fmaxf(wmx[0], wmx[1]), fmaxf(wmx[2], wmx[3]));
    pmm[blk * 2 + 0] = mn; pmm[blk * 2 + 1] = mx;
  }
}

// ---- K3 (fused): normalize -> conv13 -> exact top-8192 select -> scatter sparse ----
__global__ __launch_bounds__(1024) void k_selfuse(const float* __restrict__ y,
                                                  const float* __restrict__ pmm,
                                                  const float* __restrict__ w,
                                                  float* __restrict__ sp) {
  int b = blockIdx.x;
  int tid = threadIdx.x;
  int wave = tid >> 6;
  extern __shared__ float vsh[];            // 16896 floats, idx(j) = j + (j>>5)
  __shared__ float wl[ATT_K];
  __shared__ int red[16][16][4];            // [pass][wave][channel]
  __shared__ int wtot[16];
  if (tid < ATT_K) wl[tid] = w[tid];

  float mn = pmm[b * 32], mx = pmm[b * 32 + 1];
  #pragma unroll
  for (int t = 1; t < 16; ++t) {
    mn = fminf(mn, pmm[b * 32 + t * 2]);
    mx = fmaxf(mx, pmm[b * 32 + t * 2 + 1]);
  }
  float inv = 1.f / (mx - mn);

  const float* yb = y + b * LL;
  #pragma unroll
  for (int c = 0; c < 4; ++c) {
    int i = c * 4096 + tid * 4;
    float4 t4 = *(const float4*)(yb + i);
    int p0 = i + (i >> 5);
    vsh[p0 + 0] = (t4.x - mn) * inv;
    vsh[p0 + 1] = (t4.y - mn) * inv;
    vsh[p0 + 2] = (t4.z - mn) * inv;
    vsh[p0 + 3] = (t4.w - mn) * inv;
  }
  __syncthreads();

  int e = tid * 16;
  float v28[28];
  #pragma unroll
  for (int i = 0; i < 28; ++i) {
    int j = e - 6 + i;
    v28[i] = (j >= 0 && j < LL) ? vsh[j + (j >> 5)] : 0.f;
  }
  float s[16], v[16];
  unsigned kk[16];
  #pragma unroll
  for (int i = 0; i < 16; ++i) {
    float acc = 0.f;
    #pragma unroll
    for (int k = 0; k < ATT_K; ++k) acc += v28[i + k] * wl[k];
    s[i] = acc;
    v[i] = v28[i + 6];
    kk[i] = fkey(acc);
  }

  unsigned p = 0; int need = KLIM;
  for (int pass = 0; pass < 16; ++pass) {
    int sh = 30 - pass * 2;
    unsigned himask = (pass == 0) ? 0u : (0xFFFFFFFFu << (sh + 2));
    int c3 = 0, c2 = 0, c1 = 0;
    #pragma unroll
    for (int i = 0; i < 16; ++i) {
      unsigned k2 = kk[i];
      if ((k2 & himask) == p) {
        unsigned bk = (k2 >> sh) & 3u;
        c3 += (bk == 3); c2 += (bk == 2); c1 += (bk == 1);
      }
    }
    #pragma unroll
    for (int m = 1; m < 64; m <<= 1) {
      c3 += __shfl_xor(c3, m); c2 += __shfl_xor(c2, m); c1 += __shfl_xor(c1, m);
    }
    if ((tid & 63) == 0) { red[pass][wave][0] = c3; red[pass][wave][1] = c2; red[pass][wave][2] = c1; }
    __syncthreads();
    int C3 = 0, C2 = 0, C1 = 0;
    #pragma unroll
    for (int t = 0; t < 16; ++t) { C3 += red[pass][t][0]; C2 += red[pass][t][1]; C1 += red[pass][t][2]; }
    if (C3 >= need)                { p |= 3u << sh; }
    else if (C3 + C2 >= need)      { p |= 2u << sh; need -= C3; }
    else if (C3 + C2 + C1 >= need) { p |= 1u << sh; need -= C3 + C2; }
    else                           { need -= C3 + C2 + C1; }
  }

  int cnt = 0;
  #pragma unroll
  for (int i = 0; i < 16; ++i) cnt += (kk[i] == p);
  int pre = cnt;
  #pragma unroll
  for (int m = 1; m < 64; m <<= 1) {
    int t = __shfl_up(pre, m);
    if ((tid & 63) >= m) pre += t;
  }
  if ((tid & 63) == 63) wtot[wave] = pre;
  __syncthreads();
  int base = 0;
  for (int t = 0; t < 16; ++t) if (t < wave) base += wtot[t];
  int rank = base + pre - cnt;

  float* spb = sp + b * LL;
  #pragma unroll
  for (int i = 0; i < 16; ++i) {
    bool sel;
    if (kk[i] > p) sel = true;
    else if (kk[i] == p) { sel = (rank < need); rank++; }
    else sel = false;
    spb[e + i] = sel ? v[i] * (sigmoidf(s[i]) + 1.f) : 0.f;
  }
}

// ---- K4: h = sp @ W1^T + b1 ; barrier-free, 2 rows/wave, sp direct from L2 ----
__global__ __launch_bounds__(256) void k_gemm1(const float* __restrict__ W1, const float* __restrict__ b1,
                                               const float* __restrict__ sp, float* __restrict__ h) {
  int tid = threadIdx.x;
  int wave = tid >> 6, lane = tid & 63;
  int r0 = blockIdx.x * 8 + wave * 2;
  const float* w0p = W1 + (size_t)r0 * LL;
  const float* w1p = W1 + (size_t)(r0 + 1) * LL;
  float acc0[8], acc1[8];
  #pragma unroll
  for (int bb = 0; bb < 8; ++bb) { acc0[bb] = 0.f; acc1[bb] = 0.f; }
  #pragma unroll 2
  for (int it = 0; it < 64; ++it) {
    int j = it * 256 + lane * 4;
    f32x4 w0 = __builtin_nontemporal_load((const f32x4*)(w0p + j));
    f32x4 w1 = __builtin_nontemporal_load((const f32x4*)(w1p + j));
    #pragma unroll
    for (int bb = 0; bb < 8; ++bb) {
      f32x4 s4 = *(const f32x4*)(sp + (size_t)bb * LL + j);
      acc0[bb] += w0.x * s4.x + w0.y * s4.y + w0.z * s4.z + w0.w * s4.w;
      acc1[bb] += w1.x * s4.x + w1.y * s4.y + w1.z * s4.z + w1.w * s4.w;
    }
  }
  #pragma unroll
  for (int bb = 0; bb < 8; ++bb) {
    float a0 = acc0[bb], a1 = acc1[bb];
    #pragma unroll
    for (int m = 1; m < 64; m <<= 1) {
      a0 += __shfl_xor(a0, m);
      a1 += __shfl_xor(a1, m);
    }
    if (lane == 0) {
      h[bb * N1 + r0]     = a0 + b1[r0];
      h[bb * N1 + r0 + 1] = a1 + b1[r0 + 1];
    }
  }
}

// ---- K5: h2 = h @ W2^T + b2 ; barrier-free, 2 rows/wave, K=6000 with tail mask ----
__global__ __launch_bounds__(256) void k_gemm2(const float* __restrict__ W2, const float* __restrict__ b2,
                                               const float* __restrict__ h, float* __restrict__ h2) {
  int tid = threadIdx.x;
  int wave = tid >> 6, lane = tid & 63;
  int r0 = blockIdx.x * 8 + wave * 2;
  bool v0 = r0 < N2, v1 = (r0 + 1) < N2;
  const float* w0p = W2 + (size_t)(v0 ? r0 : 0) * N1;
  const float* w1p = W2 + (size_t)(v1 ? (r0 + 1) : 0) * N1;
  float acc0[8], acc1[8];
  #pragma unroll
  for (int bb = 0; bb < 8; ++bb) { acc0[bb] = 0.f; acc1[bb] = 0.f; }
  #pragma unroll 2
  for (int it = 0; it < 24; ++it) {
    int j = it * 256 + lane * 4;
    bool inb = j < N1;                       // N1 % 4 == 0, so full float4 in-bounds
    f32x4 z = {0.f, 0.f, 0.f, 0.f};
    f32x4 w0 = z, w1 = z;
    if (inb) {
      w0 = __builtin_nontemporal_load((const f32x4*)(w0p + j));
      w1 = __builtin_nontemporal_load((const f32x4*)(w1p + j));
    }
    #pragma unroll
    for (int bb = 0; bb < 8; ++bb) {
      f32x4 s4 = inb ? *(const f32x4*)(h + (size_t)bb * N1 + j) : z;
      acc0[bb] += w0.x * s4.x + w0.y * s4.y + w0.z * s4.z + w0.w * s4.w;
      acc1[bb] += w1.x * s4.x + w1.y * s4.y + w1.z * s4.z + w1.w * s4.w;
    }
  }
  #pragma unroll
  for (int bb = 0; bb < 8; ++bb) {
    float a0 = acc0[bb], a1 = acc1[bb];
    #pragma unroll
    for (int m = 1; m < 64; m <<= 1) {
      a0 += __shfl_xor(a0, m);
      a1 += __shfl_xor(a1, m);
    }
    if (lane == 0) {
      if (v0) h2[bb * N2 + r0]     = a0 + b2[r0];
      if (v1) h2[bb * N2 + r0 + 1] = a1 + b2[r0 + 1];
    }
  }
}

// ---- K6: t[b,m] = sum_n h2[b,n]*Wc1[m,n] ; one block per (b,m) ----
__global__ void k_cls1(const float* __restrict__ h2, const float* __restrict__ Wc1,
                       float* __restrict__ t) {
  int bid = blockIdx.x; int b = bid >> 5, m = bid & 31;
  int tid = threadIdx.x;
  const float* hb = h2 + b * N2;
  const float* wm = Wc1 + m * N2;
  float s = 0.f;
  for (int j = tid; j < N2; j += 256) s += hb[j] * wm[j];
  #pragma unroll
  for (int mm = 1; mm < 64; mm <<= 1) s += __shfl_xor(s, mm);
  __shared__ float red[4];
  if ((tid & 63) == 0) red[tid >> 6] = s;
  __syncthreads();
  if (tid == 0) t[b * 32 + m] = red[0] + red[1] + red[2] + red[3];
}

// ---- K7: logits = t @ Wc2^T ; log_softmax ----
__global__ void k_final(const float* __restrict__ t, const float* __restrict__ Wc2,
                        float* __restrict__ out) {
  int b = threadIdx.x;
  if (b < NB) {
    float lg[NCLS];
    #pragma unroll
    for (int k = 0; k < NCLS; ++k) {
      float s = 0.f;
      #pragma unroll
      for (int m = 0; m < 32; ++m) s += t[b * 32 + m] * Wc2[k * 32 + m];
      lg[k] = s;
    }
    float mx = lg[0];
    #pragma unroll
    for (int k = 1; k < NCLS; ++k) mx = fmaxf(mx, lg[k]);
    float se = 0.f;
    #pragma unroll
    for (int k = 0; k < NCLS; ++k) se += expf(lg[k] - mx);
    float lse = logf(se);
    #pragma unroll
    for (int k = 0; k < NCLS; ++k) out[b * NCLS + k] = lg[k] - mx - lse;
  }
}

extern "C" void kernel_launch(void* const* d_in, const int* in_sizes, int n_in,
                              void* d_out, int out_size, void* d_ws, size_t ws_size,
                              hipStream_t stream) {
  const float* adj   = (const float*)d_in[0];
  const float* eca_w = (const float*)d_in[1];
  const float* att_w = (const float*)d_in[2];
  const float* W1    = (const float*)d_in[3];
  const float* b1    = (const float*)d_in[4];
  const float* W2    = (const float*)d_in[5];
  const float* b2    = (const float*)d_in[6];
  const float* Wc1   = (const float*)d_in[7];
  const float* Wc2   = (const float*)d_in[8];
  float* out = (float*)d_out;
  float* ws  = (float*)d_ws;

  float* pooled = ws;              // 240
  float* pmm    = ws + 512;        // 256
  float* y      = ws + 1024;       // 131072
  float* sp     = y  + NB * LL;    // 131072
  float* h      = sp + NB * LL;    // 48000
  float* h2     = h  + NB * N1;    // 39312
  float* tbuf   = h2 + NB * N2;    // 256

  k_pool   <<<NB * NCH, 256, 0, stream>>>(adj, pooled);
  k_wsum   <<<NB * 16, 256, 0, stream>>>(adj, pooled, eca_w, y, pmm, out + NB * NCLS);
  k_selfuse<<<NB, 1024, 16896 * sizeof(float), stream>>>(y, pmm, att_w, sp);
  k_gemm1  <<<N1 / 8, 256, 0, stream>>>(W1, b1, sp, h);
  k_gemm2  <<<(N2 + 7) / 8, 256, 0, stream>>>(W2, b2, h, h2);
  k_cls1   <<<NB * 32, 256, 0, stream>>>(h2, Wc1, tbuf);
  k_final  <<<1, 64, 0, stream>>>(tbuf, Wc2, out);
}